// Round 4
// baseline (334.466 us; speedup 1.0000x reference)
//
#include <hip/hip_runtime.h>
#include <hip/hip_bf16.h>

// Chamfer loss via MFMA: predict_pc [B=4,3,N=8192] f32, gt_pc [B,3,N] f32.
// loss = sum_gt min_pred d / B + sum_pred min_gt d / B
//
// m := d^2/2 = pn + gn - p.g  (pn=|p|^2/2, gn=|g|^2/2) computed by ONE
// bf16 MFMA (16x16x32) per 16x16 tile using split-bf16 (hi+lo ~ fp32):
//   A k-slots (pred row): [-ph,-ph,-pl,-pl (3 dims each), pnh,pnl, 1,1, 0...]
//   B k-slots (gt col):   [ gh, gl, gh, gl (3 dims each), 1,1, gnh,gnl, 0...]
//   sum_k A[k]B[k] = pn + gn - (ph+pl).(gh+gl) = m  (error ~2^-18)
// Both chamfer directions come from one matrix: row-min (over gt) and
// col-min (over pred) folded in-register (float mins), merged across blocks
// via int atomicMin on clamped non-negative floats (exact, deterministic).
// d = sqrt(2*min m), summed by a two-stage tree reduction.

#define BM 256
#define BN 256
#define LDK 40      // padded per-point k-stride in shorts (32 + 8 pad)
#define RBLKS 64

typedef short short8 __attribute__((ext_vector_type(8)));
typedef float f32x4 __attribute__((ext_vector_type(4)));

static __device__ inline unsigned short f2bf(float f) {
    __hip_bfloat16 h = __float2bfloat16(f);
    return *reinterpret_cast<unsigned short*>(&h);
}
static __device__ inline float bf2f(unsigned short u) {
    __hip_bfloat16 h;
    *reinterpret_cast<unsigned short*>(&h) = u;
    return __bfloat162float(h);
}

__global__ __launch_bounds__(256, 3) void chamfer_mfma_kernel(
    const float* __restrict__ pred, const float* __restrict__ gt,
    int* __restrict__ rowmin_g,   // [B,N] min m for each pred point (z2)
    int* __restrict__ colmin_g,   // [B,N] min m for each gt point   (z)
    int N, int mt)                // mt = N/256 tiles per dim
{
    __shared__ unsigned short A_lds[BM * LDK];
    __shared__ unsigned short B_lds[BN * LDK];
    __shared__ int colmin_s[BN];

    int bid = blockIdx.x;
    int ct = bid % mt;
    int rt = (bid / mt) % mt;
    int b  = bid / (mt * mt);

    int tid = threadIdx.x;
    const float* pb = pred + (size_t)b * 3 * N;
    const float* gb = gt   + (size_t)b * 3 * N;

    colmin_s[tid] = 0x7F7F7F7F;
    const unsigned short ONE = 0x3F80;  // bf16(1.0)

    // ---- stage A: pred rows (negated hi/lo split + pn split) ----
    {
        int ia = rt * BM + tid;
        float x = pb[ia], y = pb[N + ia], z = pb[2 * N + ia];
        unsigned short hx = f2bf(x), hy = f2bf(y), hz = f2bf(z);
        unsigned short lx = f2bf(x - bf2f(hx)), ly = f2bf(y - bf2f(hy)),
                       lz = f2bf(z - bf2f(hz));
        float pn = 0.5f * (x * x + y * y + z * z);
        unsigned short pnh = f2bf(pn), pnl = f2bf(pn - bf2f(pnh));
        __align__(16) unsigned short row[16] = {
            (unsigned short)(hx ^ 0x8000), (unsigned short)(hy ^ 0x8000),
            (unsigned short)(hz ^ 0x8000), (unsigned short)(hx ^ 0x8000),
            (unsigned short)(hy ^ 0x8000), (unsigned short)(hz ^ 0x8000),
            (unsigned short)(lx ^ 0x8000), (unsigned short)(ly ^ 0x8000),
            (unsigned short)(lz ^ 0x8000), (unsigned short)(lx ^ 0x8000),
            (unsigned short)(ly ^ 0x8000), (unsigned short)(lz ^ 0x8000),
            pnh, pnl, ONE, ONE};
        unsigned short* dst = A_lds + tid * LDK;
        *(short8*)(dst + 0)  = ((const short8*)row)[0];
        *(short8*)(dst + 8)  = ((const short8*)row)[1];
        *(short8*)(dst + 16) = (short8)0;
        *(short8*)(dst + 24) = (short8)0;
    }
    // ---- stage B: gt cols (hi/lo split + gn split) ----
    {
        int ib = ct * BN + tid;
        float x = gb[ib], y = gb[N + ib], z = gb[2 * N + ib];
        unsigned short hx = f2bf(x), hy = f2bf(y), hz = f2bf(z);
        unsigned short lx = f2bf(x - bf2f(hx)), ly = f2bf(y - bf2f(hy)),
                       lz = f2bf(z - bf2f(hz));
        float gn = 0.5f * (x * x + y * y + z * z);
        unsigned short gnh = f2bf(gn), gnl = f2bf(gn - bf2f(gnh));
        __align__(16) unsigned short row[16] = {
            hx, hy, hz, lx, ly, lz, hx, hy, hz, lx, ly, lz,
            ONE, ONE, gnh, gnl};
        unsigned short* dst = B_lds + tid * LDK;
        *(short8*)(dst + 0)  = ((const short8*)row)[0];
        *(short8*)(dst + 8)  = ((const short8*)row)[1];
        *(short8*)(dst + 16) = (short8)0;
        *(short8*)(dst + 24) = (short8)0;
    }
    __syncthreads();

    int lane = tid & 63, w = tid >> 6;
    int lrow = lane & 15, kg = lane >> 4;   // frag row/col lane, k-group

    // A fragments for this wave's 64-row strip (rows w*64 .. +64)
    short8 afrag[4];
    #pragma unroll
    for (int i = 0; i < 4; ++i)
        afrag[i] = *(const short8*)(A_lds + (w * 64 + i * 16 + lrow) * LDK + kg * 8);

    float rmn[4][4], cmn[16];
    #pragma unroll
    for (int i = 0; i < 4; ++i)
        #pragma unroll
        for (int r = 0; r < 4; ++r) rmn[i][r] = 3.0e38f;
    #pragma unroll
    for (int j = 0; j < 16; ++j) cmn[j] = 3.0e38f;

    const f32x4 zero4 = {0.f, 0.f, 0.f, 0.f};

    // full unroll: j must be compile-time (cmn[j] in registers, not scratch)
    #pragma unroll
    for (int j = 0; j < 16; ++j) {
        short8 bfrag = *(const short8*)(B_lds + (j * 16 + lrow) * LDK + kg * 8);
        #pragma unroll
        for (int i = 0; i < 4; ++i) {
            f32x4 acc = __builtin_amdgcn_mfma_f32_16x16x32_bf16(
                afrag[i], bfrag, zero4, 0, 0, 0);
            rmn[i][0] = fminf(rmn[i][0], acc[0]);
            rmn[i][1] = fminf(rmn[i][1], acc[1]);
            rmn[i][2] = fminf(rmn[i][2], acc[2]);
            rmn[i][3] = fminf(rmn[i][3], acc[3]);
            cmn[j] = fminf(cmn[j],
                     fminf(fminf(acc[0], acc[1]), fminf(acc[2], acc[3])));
        }
    }

    // ---- row mins: reduce across 16 cols held in lanes (bits 0-3) ----
    #pragma unroll
    for (int s = 1; s <= 8; s <<= 1)
        #pragma unroll
        for (int i = 0; i < 4; ++i)
            #pragma unroll
            for (int r = 0; r < 4; ++r)
                rmn[i][r] = fminf(rmn[i][r], __shfl_xor(rmn[i][r], s, 64));
    if (lrow == 0) {
        int rbase = b * N + rt * BM + w * 64 + kg * 4;
        #pragma unroll
        for (int i = 0; i < 4; ++i)
            #pragma unroll
            for (int r = 0; r < 4; ++r)
                atomicMin(&rowmin_g[rbase + i * 16 + r],
                          __float_as_int(fmaxf(rmn[i][r], 0.0f)));
    }

    // ---- col mins: reduce across 4 row-groups (bits 4-5), fold via LDS ----
    #pragma unroll
    for (int s = 16; s <= 32; s <<= 1)
        #pragma unroll
        for (int j = 0; j < 16; ++j)
            cmn[j] = fminf(cmn[j], __shfl_xor(cmn[j], s, 64));
    if (kg == 0) {
        #pragma unroll
        for (int j = 0; j < 16; ++j)
            atomicMin(&colmin_s[j * 16 + lrow],
                      __float_as_int(fmaxf(cmn[j], 0.0f)));
    }
    __syncthreads();
    atomicMin(&colmin_g[b * N + ct * BN + tid], colmin_s[tid]);
}

__global__ __launch_bounds__(256) void chamfer_reduce1_kernel(
    const int* __restrict__ minbuf, float* __restrict__ partials, int per_blk)
{
    __shared__ float sdata[256];
    int base = blockIdx.x * per_blk + threadIdx.x;
    float s = 0.0f;
    for (int k = 0; k < per_blk; k += 256) {
        float m = __int_as_float(minbuf[base + k]);
        s += sqrtf(fmaxf(2.0f * m, 0.0f));   // d = sqrt(2*m), m = d^2/2
    }
    sdata[threadIdx.x] = s;
    __syncthreads();
    for (int off = 128; off > 0; off >>= 1) {
        if (threadIdx.x < off) sdata[threadIdx.x] += sdata[threadIdx.x + off];
        __syncthreads();
    }
    if (threadIdx.x == 0) partials[blockIdx.x] = sdata[0];
}

__global__ __launch_bounds__(64) void chamfer_reduce2_kernel(
    const float* __restrict__ partials, float* __restrict__ out, float inv_b)
{
    __shared__ float sdata[64];
    sdata[threadIdx.x] = partials[threadIdx.x];
    __syncthreads();
    for (int off = 32; off > 0; off >>= 1) {
        if (threadIdx.x < off) sdata[threadIdx.x] += sdata[threadIdx.x + off];
        __syncthreads();
    }
    if (threadIdx.x == 0) out[0] = sdata[0] * inv_b;
}

extern "C" void kernel_launch(void* const* d_in, const int* in_sizes, int n_in,
                              void* d_out, int out_size, void* d_ws, size_t ws_size,
                              hipStream_t stream) {
    const float* pred = (const float*)d_in[0];
    const float* gt   = (const float*)d_in[1];
    const int B = 4, D = 3;
    const int N = in_sizes[0] / (B * D);   // 8192
    const int total = 2 * B * N;           // 65536

    int* minbuf = (int*)d_ws;              // [2][B][N] ints = 512 KB
    float* partials = (float*)((char*)d_ws + (size_t)total * sizeof(int));
    // 0x7F7F7F7F as float = 3.39e38 -> +inf sentinel for int-min
    hipMemsetAsync(d_ws, 0x7F, (size_t)total * sizeof(int), stream);

    int* rowmin_g = minbuf;            // pred-side mins (z2)
    int* colmin_g = minbuf + B * N;    // gt-side mins  (z)

    int mt = N / BM;                   // 32
    chamfer_mfma_kernel<<<dim3(B * mt * mt), dim3(256), 0, stream>>>(
        pred, gt, rowmin_g, colmin_g, N, mt);

    chamfer_reduce1_kernel<<<dim3(RBLKS), dim3(256), 0, stream>>>(
        minbuf, partials, total / RBLKS);
    chamfer_reduce2_kernel<<<dim3(1), dim3(64), 0, stream>>>(
        partials, (float*)d_out, 1.0f / B);
}

// Round 6
// 40.060 us; speedup vs baseline: 8.3491x; 8.3491x over previous
//
#include <hip/hip_runtime.h>
#include <hip/hip_bf16.h>

// Chamfer loss via MFMA, atomic-free: predict_pc [B=4,3,N=8192] f32, gt [B,3,N].
// loss = sum_gt min_pred d / B + sum_pred min_gt d / B
//
// m := d^2/2 = on + qn - o.q via bf16 MFMA 16x16x32 with split-bf16 (hi+lo,
// ~fp32; packing validated end-to-end in R4, absmax 0.0):
//   A record (opposite row): [-oh(3),-oh(3),-ol(3),-ol(3), onh,onl, 1,1, 0*16]
//   B record (query col):    [ qh(3), ql(3), qh(3), ql(3), 1,1, qnh,qnl, 0*16]
// Roles per verified GEMM convention (A rows = lane&15 input / output rows =
// (lane>>4)*4+reg, output cols = lane&15 = B cols): acc's 4 elems per lane are
// 4 opposite rows of ONE query column -> fold is a chained fminf (compiler
// fuses to v_min3_f32 with correct MFMA-read hazards; no inline asm).
// Block = 256 queries (B-frags in registers) x one opposite strip streamed
// through LDS in 256-point chunks. One plain store per query per block into
// partial[(dir*4+b)*ncs+cs][N]; reduce pass min-merges + sqrt + sums.
// No atomics, no memset, deterministic.

#define NQ 256      // queries per block
#define OC 256      // opposite points per LDS chunk
#define LDK 40      // record stride in shorts (32 + 8 pad), R4-proven
#define RBLKS 64

typedef short short8 __attribute__((ext_vector_type(8)));
typedef float f32x4 __attribute__((ext_vector_type(4)));

static __device__ inline unsigned short f2bf(float f) {
    __hip_bfloat16 h = __float2bfloat16(f);
    return *reinterpret_cast<unsigned short*>(&h);
}
static __device__ inline float bf2f(unsigned short u) {
    __hip_bfloat16 h;
    *reinterpret_cast<unsigned short*>(&h) = u;
    return __bfloat162float(h);
}
static __device__ inline void split_bf(float v, unsigned short& hi,
                                       unsigned short& lo) {
    hi = f2bf(v);
    lo = f2bf(v - bf2f(hi));
}

__global__ __launch_bounds__(256, 4) void chamfer_mfma_kernel(
    const float* __restrict__ pred, const float* __restrict__ gt,
    float* __restrict__ partial,   // [(dir*4+b)*ncs+cs][N]
    int N, int ncs, int nchunks, int qtiles)
{
    __shared__ unsigned short q_lds[NQ * LDK];  // 20 KB
    __shared__ unsigned short o_lds[OC * LDK];  // 20 KB

    int bid = blockIdx.x;
    int cs = bid % ncs;   int t1 = bid / ncs;
    int qt = t1 % qtiles; int t2 = t1 / qtiles;
    int b  = t2 & 3;      int dir = t2 >> 2;

    const float* qpts = dir ? pred : gt;   // dir0: queries=gt (z)
    const float* opts = dir ? gt   : pred; // dir1: queries=pred (z2)
    const float* qb = qpts + (size_t)b * 3 * N;
    const float* ob = opts + (size_t)b * 3 * N;

    int tid = threadIdx.x;
    const unsigned short ONE = 0x3F80;

    // ---- stage this block's 256 queries (B-side packing, k16-31 zeroed) ----
    {
        int qi = qt * NQ + tid;
        float x = qb[qi], y = qb[N + qi], z = qb[2 * N + qi];
        unsigned short hx, lx, hy, ly, hz, lz, nh, nl;
        split_bf(x, hx, lx); split_bf(y, hy, ly); split_bf(z, hz, lz);
        float qn = 0.5f * fmaf(x, x, fmaf(y, y, z * z));
        split_bf(qn, nh, nl);
        __align__(16) unsigned short r[16] = {
            hx, hy, hz, lx, ly, lz, hx, hy, hz, lx, ly, lz, ONE, ONE, nh, nl};
        unsigned short* dst = q_lds + tid * LDK;
        *(short8*)(dst + 0)  = ((const short8*)r)[0];
        *(short8*)(dst + 8)  = ((const short8*)r)[1];
        *(short8*)(dst + 16) = (short8)0;
        *(short8*)(dst + 24) = (short8)0;
    }
    __syncthreads();

    int lane = tid & 63, w = tid >> 6;
    int lrow = lane & 15, kg = lane >> 4;

    // B-frags: this wave's 64 query columns, in registers for whole kernel
    short8 bfrag[4];
    #pragma unroll
    for (int j = 0; j < 4; ++j)
        bfrag[j] = *(const short8*)(q_lds + (w * 64 + j * 16 + lrow) * LDK + kg * 8);

    float mn[4] = {3.0e38f, 3.0e38f, 3.0e38f, 3.0e38f};
    const f32x4 zero4 = {0.f, 0.f, 0.f, 0.f};
    int obase = cs * nchunks * OC;

    for (int c = 0; c < nchunks; ++c) {
        __syncthreads();   // previous chunk's reads done before overwrite
        {   // stage opposite chunk (A-side packing, negated, k16-31 zeroed)
            int oi = obase + c * OC + tid;
            float x = ob[oi], y = ob[N + oi], z = ob[2 * N + oi];
            unsigned short hx, lx, hy, ly, hz, lz, nh, nl;
            split_bf(x, hx, lx); split_bf(y, hy, ly); split_bf(z, hz, lz);
            float on = 0.5f * fmaf(x, x, fmaf(y, y, z * z));
            split_bf(on, nh, nl);
            __align__(16) unsigned short r[16] = {
                (unsigned short)(hx ^ 0x8000), (unsigned short)(hy ^ 0x8000),
                (unsigned short)(hz ^ 0x8000), (unsigned short)(hx ^ 0x8000),
                (unsigned short)(hy ^ 0x8000), (unsigned short)(hz ^ 0x8000),
                (unsigned short)(lx ^ 0x8000), (unsigned short)(ly ^ 0x8000),
                (unsigned short)(lz ^ 0x8000), (unsigned short)(lx ^ 0x8000),
                (unsigned short)(ly ^ 0x8000), (unsigned short)(lz ^ 0x8000),
                nh, nl, ONE, ONE};
            unsigned short* dst = o_lds + tid * LDK;
            *(short8*)(dst + 0)  = ((const short8*)r)[0];
            *(short8*)(dst + 8)  = ((const short8*)r)[1];
            *(short8*)(dst + 16) = (short8)0;
            *(short8*)(dst + 24) = (short8)0;
        }
        __syncthreads();

        #pragma unroll
        for (int i = 0; i < 16; ++i) {
            short8 af = *(const short8*)(o_lds + (i * 16 + lrow) * LDK + kg * 8);
            #pragma unroll
            for (int j = 0; j < 4; ++j) {
                f32x4 acc = __builtin_amdgcn_mfma_f32_16x16x32_bf16(
                    af, bfrag[j], zero4, 0, 0, 0);
                // chained: clang fuses into 2x v_min3_f32 with proper hazards
                mn[j] = fminf(fminf(fminf(fminf(mn[j], acc[0]), acc[1]),
                                    acc[2]), acc[3]);
            }
        }
    }

    // fold the 4 row-groups (kg lanes) of each query column
    #pragma unroll
    for (int j = 0; j < 4; ++j) {
        mn[j] = fminf(mn[j], __shfl_xor(mn[j], 16, 64));
        mn[j] = fminf(mn[j], __shfl_xor(mn[j], 32, 64));
    }
    if (lane < 16) {
        float* pp = partial + ((size_t)((dir * 4 + b) * ncs + cs)) * N
                  + qt * NQ + w * 64;
        #pragma unroll
        for (int j = 0; j < 4; ++j) pp[j * 16 + lane] = mn[j];
    }
}

__global__ __launch_bounds__(256) void chamfer_reduce1_kernel(
    const float* __restrict__ partial, float* __restrict__ partials2,
    int N, int ncs, int iters)
{
    __shared__ float sdata[256];
    float s = 0.0f;
    for (int k = 0; k < iters; ++k) {
        int L = blockIdx.x * (iters * 256) + k * 256 + threadIdx.x;
        int row = L / N, q = L - row * N;
        const float* pp = partial + (size_t)row * ncs * N + q;
        float v = pp[0];
        for (int cs = 1; cs < ncs; ++cs) v = fminf(v, pp[(size_t)cs * N]);
        s += sqrtf(fmaxf(2.0f * v, 0.0f));   // d = sqrt(2m)
    }
    sdata[threadIdx.x] = s;
    __syncthreads();
    for (int off = 128; off > 0; off >>= 1) {
        if (threadIdx.x < off) sdata[threadIdx.x] += sdata[threadIdx.x + off];
        __syncthreads();
    }
    if (threadIdx.x == 0) partials2[blockIdx.x] = sdata[0];
}

__global__ __launch_bounds__(64) void chamfer_reduce2_kernel(
    const float* __restrict__ partials2, float* __restrict__ out, float inv_b)
{
    __shared__ float sdata[64];
    sdata[threadIdx.x] = partials2[threadIdx.x];
    __syncthreads();
    for (int off = 32; off > 0; off >>= 1) {
        if (threadIdx.x < off) sdata[threadIdx.x] += sdata[threadIdx.x + off];
        __syncthreads();
    }
    if (threadIdx.x == 0) out[0] = sdata[0] * inv_b;
}

extern "C" void kernel_launch(void* const* d_in, const int* in_sizes, int n_in,
                              void* d_out, int out_size, void* d_ws, size_t ws_size,
                              hipStream_t stream) {
    const float* pred = (const float*)d_in[0];
    const float* gt   = (const float*)d_in[1];
    const int B = 4, D = 3;
    const int N = in_sizes[0] / (B * D);   // 8192

    // strip count bounded by workspace: bytes = 2*B*ncs*N*4 + RBLKS*4
    int ncs = 4;
    while (ncs > 1 &&
           ws_size < (size_t)2 * B * ncs * N * sizeof(float) + RBLKS * sizeof(float))
        ncs >>= 1;

    float* partial   = (float*)d_ws;                       // [2*B*ncs][N]
    float* partials2 = partial + (size_t)2 * B * ncs * N;  // [RBLKS]

    int qtiles  = N / NQ;            // 32
    int nchunks = N / (ncs * OC);    // 8 at ncs=4
    dim3 grid1(2 * B * qtiles * ncs);
    chamfer_mfma_kernel<<<grid1, dim3(256), 0, stream>>>(
        pred, gt, partial, N, ncs, nchunks, qtiles);

    int iters = (2 * B * N) / (RBLKS * 256);   // 4
    chamfer_reduce1_kernel<<<dim3(RBLKS), dim3(256), 0, stream>>>(
        partial, partials2, N, ncs, iters);
    chamfer_reduce2_kernel<<<dim3(1), dim3(64), 0, stream>>>(
        partials2, (float*)d_out, 1.0f / B);
}

// Round 7
// 35.021 us; speedup vs baseline: 9.5505x; 1.1439x over previous
//
#include <hip/hip_runtime.h>
#include <hip/hip_bf16.h>

// Chamfer loss via 32x32x16 MFMA, atomic-free.
// predict_pc [B=4,3,N=8192] f32, gt_pc [B,3,N] f32.
// loss = sum_gt min_pred d / B + sum_pred min_gt d / B
//
// m := d^2/2 = on + qn - o.q via bf16 MFMA 32x32x16 with split-bf16 (hi+lo
// ~ fp32). K=16 fits the packing EXACTLY (content identical to the
// R4/R6-validated records, first 16 slots):
//   A (opposite row): [-oh(3), -oh(3), -ol(3), -ol(3), onh, onl, 1, 1]
//   B (query col):    [ qh(3),  ql(3),  qh(3),  ql(3), 1, 1, qnh, qnl]
//   sum_k A[k]B[k] = on + qn - (oh+ol).(qh+ql) = m   (all 4 cross terms)
// Records are 16 shorts padded to stride 24 (48 B -> bank-uniform b128).
// Fragment layout 32x32x16: A row / B col = lane&31, k-half = lane>>5;
// C/D: col = lane&31, row = (reg&3) + 8*(reg>>2) + 4*(lane>>5)  [m74/m101].
// Each wave holds 4 B-frags (128 query cols) in registers; A streams from
// LDS (1 KB per 4096 outputs). Per-MFMA fold: 8-op min3 tree into mn[j].
// One plain store per query per block into partial[(dir*4+b)*ncs+cs][N];
// reduce pass min-merges strips + sqrt + sums. No atomics, no memset.

#define NQ 512      // queries per block (4 waves x 128)
#define OC 256      // opposite points per LDS chunk
#define LDR 24      // record stride in shorts (16 + 8 pad = 48 B)
#define JF 4        // B-frags per wave
#define RBLKS 64

typedef short short8 __attribute__((ext_vector_type(8)));
typedef float f32x16 __attribute__((ext_vector_type(16)));

static __device__ inline unsigned short f2bf(float f) {
    __hip_bfloat16 h = __float2bfloat16(f);
    return *reinterpret_cast<unsigned short*>(&h);
}
static __device__ inline float bf2f(unsigned short u) {
    __hip_bfloat16 h;
    *reinterpret_cast<unsigned short*>(&h) = u;
    return __bfloat162float(h);
}
static __device__ inline void split_bf(float v, unsigned short& hi,
                                       unsigned short& lo) {
    hi = f2bf(v);
    lo = f2bf(v - bf2f(hi));
}
static __device__ inline float min3f(float a, float b, float c) {
    return fminf(fminf(a, b), c);   // clang fuses to v_min3_f32
}

__global__ __launch_bounds__(256, 4) void chamfer_mfma_kernel(
    const float* __restrict__ pred, const float* __restrict__ gt,
    float* __restrict__ partial,   // [(dir*4+b)*ncs+cs][N]
    int N, int ncs, int nchunks, int qtiles)
{
    __align__(16) __shared__ unsigned short q_lds[NQ * LDR];  // 24 KB
    __align__(16) __shared__ unsigned short o_lds[OC * LDR];  // 12 KB

    int bid = blockIdx.x;
    int cs = bid % ncs;   int t1 = bid / ncs;
    int qt = t1 % qtiles; int t2 = t1 / qtiles;
    int b  = t2 & 3;      int dir = t2 >> 2;

    const float* qpts = dir ? pred : gt;   // dir0: queries=gt (z)
    const float* opts = dir ? gt   : pred; // dir1: queries=pred (z2)
    const float* qb = qpts + (size_t)b * 3 * N;
    const float* ob = opts + (size_t)b * 3 * N;

    int tid = threadIdx.x;
    const unsigned short ONE = 0x3F80;

    // ---- stage this block's 512 queries (B-side records) ----
    for (int s = tid; s < NQ; s += 256) {
        int qi = qt * NQ + s;
        float x = qb[qi], y = qb[N + qi], z = qb[2 * N + qi];
        unsigned short hx, lx, hy, ly, hz, lz, nh, nl;
        split_bf(x, hx, lx); split_bf(y, hy, ly); split_bf(z, hz, lz);
        float qn = 0.5f * fmaf(x, x, fmaf(y, y, z * z));
        split_bf(qn, nh, nl);
        __align__(16) unsigned short r[16] = {
            hx, hy, hz, lx, ly, lz, hx, hy, hz, lx, ly, lz, ONE, ONE, nh, nl};
        unsigned short* dst = q_lds + s * LDR;
        *(short8*)(dst + 0) = ((const short8*)r)[0];
        *(short8*)(dst + 8) = ((const short8*)r)[1];
    }
    __syncthreads();

    int lane = tid & 63, w = tid >> 6;
    int col = lane & 31, h = lane >> 5;

    // B-frags: this wave's 128 query columns, registers for whole kernel
    short8 bfrag[JF];
    #pragma unroll
    for (int j = 0; j < JF; ++j)
        bfrag[j] = *(const short8*)(q_lds + (w * 128 + j * 32 + col) * LDR + h * 8);

    float mn[JF] = {3.0e38f, 3.0e38f, 3.0e38f, 3.0e38f};
    const f32x16 zero16 = {0.f};
    int obase = cs * nchunks * OC;

    for (int c = 0; c < nchunks; ++c) {
        __syncthreads();   // previous chunk's reads done before overwrite
        {   // stage opposite chunk (A-side records, negated), 1/thread
            int oi = obase + c * OC + tid;
            float x = ob[oi], y = ob[N + oi], z = ob[2 * N + oi];
            unsigned short hx, lx, hy, ly, hz, lz, nh, nl;
            split_bf(x, hx, lx); split_bf(y, hy, ly); split_bf(z, hz, lz);
            float on = 0.5f * fmaf(x, x, fmaf(y, y, z * z));
            split_bf(on, nh, nl);
            __align__(16) unsigned short r[16] = {
                (unsigned short)(hx ^ 0x8000), (unsigned short)(hy ^ 0x8000),
                (unsigned short)(hz ^ 0x8000), (unsigned short)(hx ^ 0x8000),
                (unsigned short)(hy ^ 0x8000), (unsigned short)(hz ^ 0x8000),
                (unsigned short)(lx ^ 0x8000), (unsigned short)(ly ^ 0x8000),
                (unsigned short)(lz ^ 0x8000), (unsigned short)(lx ^ 0x8000),
                (unsigned short)(ly ^ 0x8000), (unsigned short)(lz ^ 0x8000),
                nh, nl, ONE, ONE};
            unsigned short* dst = o_lds + tid * LDR;
            *(short8*)(dst + 0) = ((const short8*)r)[0];
            *(short8*)(dst + 8) = ((const short8*)r)[1];
        }
        __syncthreads();

        #pragma unroll
        for (int i = 0; i < OC / 32; ++i) {
            short8 af = *(const short8*)(o_lds + (i * 32 + col) * LDR + h * 8);
            #pragma unroll
            for (int j = 0; j < JF; ++j) {
                f32x16 acc = __builtin_amdgcn_mfma_f32_32x32x16_bf16(
                    af, bfrag[j], zero16, 0, 0, 0);
                float l0 = min3f(acc[0],  acc[1],  acc[2]);
                float l1 = min3f(acc[3],  acc[4],  acc[5]);
                float l2 = min3f(acc[6],  acc[7],  acc[8]);
                float l3 = min3f(acc[9],  acc[10], acc[11]);
                float l4 = min3f(acc[12], acc[13], acc[14]);
                float m0 = min3f(l0, l1, l2);
                float m1 = min3f(l3, l4, acc[15]);
                mn[j] = min3f(m0, m1, mn[j]);
            }
        }
    }

    // fold the two k-half lane groups (rows +4h) of each query column
    #pragma unroll
    for (int j = 0; j < JF; ++j)
        mn[j] = fminf(mn[j], __shfl_xor(mn[j], 32, 64));

    if (lane < 32) {
        float* pp = partial + ((size_t)((dir * 4 + b) * ncs + cs)) * N
                  + qt * NQ + w * 128 + col;
        #pragma unroll
        for (int j = 0; j < JF; ++j) pp[j * 32] = mn[j];
    }
}

__global__ __launch_bounds__(256) void chamfer_reduce1_kernel(
    const float* __restrict__ partial, float* __restrict__ partials2,
    int N, int ncs, int iters)
{
    __shared__ float sdata[256];
    float s = 0.0f;
    for (int k = 0; k < iters; ++k) {
        int L = blockIdx.x * (iters * 256) + k * 256 + threadIdx.x;
        int row = L / N, q = L - row * N;
        const float* pp = partial + (size_t)row * ncs * N + q;
        float v = pp[0];
        for (int cs = 1; cs < ncs; ++cs) v = fminf(v, pp[(size_t)cs * N]);
        s += sqrtf(fmaxf(2.0f * v, 0.0f));   // d = sqrt(2m)
    }
    sdata[threadIdx.x] = s;
    __syncthreads();
    for (int off = 128; off > 0; off >>= 1) {
        if (threadIdx.x < off) sdata[threadIdx.x] += sdata[threadIdx.x + off];
        __syncthreads();
    }
    if (threadIdx.x == 0) partials2[blockIdx.x] = sdata[0];
}

__global__ __launch_bounds__(64) void chamfer_reduce2_kernel(
    const float* __restrict__ partials2, float* __restrict__ out, float inv_b)
{
    __shared__ float sdata[64];
    sdata[threadIdx.x] = partials2[threadIdx.x];
    __syncthreads();
    for (int off = 32; off > 0; off >>= 1) {
        if (threadIdx.x < off) sdata[threadIdx.x] += sdata[threadIdx.x + off];
        __syncthreads();
    }
    if (threadIdx.x == 0) out[0] = sdata[0] * inv_b;
}

extern "C" void kernel_launch(void* const* d_in, const int* in_sizes, int n_in,
                              void* d_out, int out_size, void* d_ws, size_t ws_size,
                              hipStream_t stream) {
    const float* pred = (const float*)d_in[0];
    const float* gt   = (const float*)d_in[1];
    const int B = 4, D = 3;
    const int N = in_sizes[0] / (B * D);   // 8192

    // strip count bounded by workspace: bytes = 2*B*ncs*N*4 + RBLKS*4
    int ncs = 8;
    while (ncs > 1 &&
           ws_size < (size_t)2 * B * ncs * N * sizeof(float) + RBLKS * sizeof(float))
        ncs >>= 1;

    float* partial   = (float*)d_ws;                       // [2*B*ncs][N]
    float* partials2 = partial + (size_t)2 * B * ncs * N;  // [RBLKS]

    int qtiles  = N / NQ;            // 16
    int nchunks = N / (ncs * OC);    // 4 at ncs=8
    dim3 grid1(2 * B * qtiles * ncs);  // 1024 at ncs=8
    chamfer_mfma_kernel<<<grid1, dim3(256), 0, stream>>>(
        pred, gt, partial, N, ncs, nchunks, qtiles);

    int iters = (2 * B * N) / (RBLKS * 256);   // 4
    chamfer_reduce1_kernel<<<dim3(RBLKS), dim3(256), 0, stream>>>(
        partial, partials2, N, ncs, iters);
    chamfer_reduce2_kernel<<<dim3(1), dim3(64), 0, stream>>>(
        partials2, (float*)d_out, 1.0f / B);
}